// Round 11
// baseline (211.952 us; speedup 1.0000x reference)
//
#include <hip/hip_runtime.h>

#define NN 20000
#define DD 128
#define HH 128
#define G4 512
#define DEG 32
#define NPB 48      // nodes per block: 3 MFMA groups of 16
#define NBLK 417    // ceil(NN/NPB) -- single co-resident epoch (417 <= 512 slots)

typedef __attribute__((ext_vector_type(4))) float f32x4;
typedef __attribute__((ext_vector_type(8))) short s16x8;

#ifndef __has_builtin
#define __has_builtin(x) 0
#endif

// Builtin transcendentals ONLY (round-9 lesson: raw inline-asm v_exp/v_rcp bypasses
// the compiler's trans-use hazard handling -> numerical corruption).
static __device__ __forceinline__ float fexp2(float x){
#if __has_builtin(__builtin_amdgcn_exp2f)
  return __builtin_amdgcn_exp2f(x);
#else
  return exp2f(x);
#endif
}
static __device__ __forceinline__ float frcp(float x){
#if __has_builtin(__builtin_amdgcn_rcpf)
  return __builtin_amdgcn_rcpf(x);
#else
  return 1.f/x;
#endif
}

// packed f32x2 -> bf16x2 (RNE) — VOP3, no trans hazard; proven since round 1
static __device__ __forceinline__ unsigned cvt_pk_bf16(float lo, float hi){
  unsigned r;
  asm("v_cvt_pk_bf16_f32 %0, %1, %2" : "=v"(r) : "v"(lo), "v"(hi));
  return r;
}
static __device__ __forceinline__ s16x8 ld8bf(const float* __restrict__ p){
  f32x4 a = *(const f32x4*)p;
  f32x4 b = *(const f32x4*)(p+4);
  union{unsigned u[4]; s16x8 v;} z;
  z.u[0]=cvt_pk_bf16(a[0],a[1]);
  z.u[1]=cvt_pk_bf16(a[2],a[3]);
  z.u[2]=cvt_pk_bf16(b[0],b[1]);
  z.u[3]=cvt_pk_bf16(b[2],b[3]);
  return z.v;
}
// scaled variant: multiply by s before bf16 conversion (log2e pre-scaling)
static __device__ __forceinline__ s16x8 ld8bf_s(const float* __restrict__ p, float s){
  f32x4 a = *(const f32x4*)p;
  f32x4 b = *(const f32x4*)(p+4);
  union{unsigned u[4]; s16x8 v;} z;
  z.u[0]=cvt_pk_bf16(a[0]*s,a[1]*s);
  z.u[1]=cvt_pk_bf16(a[2]*s,a[3]*s);
  z.u[2]=cvt_pk_bf16(b[0]*s,b[1]*s);
  z.u[3]=cvt_pk_bf16(b[2]*s,b[3]*s);
  return z.v;
}
// bf16 packed in u32 -> f32 (bf16 in high 16 bits IS the f32 bit pattern)
static __device__ __forceinline__ float lo16f(unsigned u){
  union{unsigned x; float f;} v; v.x = u << 16; return v.f;
}
static __device__ __forceinline__ float hi16f(unsigned u){
  union{unsigned x; float f;} v; v.x = u & 0xffff0000u; return v.f;
}
#define NLOG2E -1.44269504f
#define TLOG2E  2.88539008f

// ---------------- Phase 1: Hp = (h @ W_ih^T + b_ih + b_hh) * S[gate], bf16 ----------------
// PERMUTED layout: element (n, gatecol=128g+16w+4hi+r) stored at n*512 + w*64 + hi*16 + g*4 + r.
// PRE-SCALED by S = {-log2e, -log2e, 2log2e, -log2e} per gate (acc feeds exp2 directly).
__global__ __launch_bounds__(512,2) void k_hp(
    const float* __restrict__ h, const float* __restrict__ W_ih,
    const float* __restrict__ b_ih, const float* __restrict__ b_hh,
    unsigned short* __restrict__ Hp)
{
  const int tid=threadIdx.x, w=tid>>6, lane=tid&63, lo=lane&15, hi=lane>>4;
  const float SC[4]={NLOG2E,NLOG2E,TLOG2E,NLOG2E};
  s16x8 A[4][4];
#pragma unroll
  for(int g=0;g<4;++g){
    const float* wr=W_ih+(size_t)(128*g+16*w+lo)*DD+8*hi;
#pragma unroll
    for(int c=0;c<4;++c) A[g][c]=ld8bf_s(wr+32*c, SC[g]);
  }
  f32x4 bb[4];
#pragma unroll
  for(int g=0;g<4;++g){
    const int gcb=128*g+16*w+4*hi;
    bb[g]=(*(const f32x4*)(b_ih+gcb) + *(const f32x4*)(b_hh+gcb))*SC[g];
  }
  // grid 256, blocks 0..56 take a second 64-node chunk (313 chunks total)
  const int nchunk = (blockIdx.x < 57) ? 2 : 1;
  for(int cc=0; cc<nchunk; ++cc){
    const int n0 = ((cc? 256+blockIdx.x : blockIdx.x))*64;
    f32x4 acc[4][4];
#pragma unroll
    for(int g=0;g<4;++g)
#pragma unroll
      for(int nt=0;nt<4;++nt) acc[g][nt]=(f32x4)0.f;
#pragma unroll
    for(int c=0;c<4;++c){
      s16x8 B[4];
#pragma unroll
      for(int nt=0;nt<4;++nt){
        int nd=n0+16*nt+lo; if(nd>=NN) nd=NN-1;
        B[nt]=ld8bf(h+(size_t)nd*DD+32*c+8*hi);
      }
#pragma unroll
      for(int g=0;g<4;++g)
#pragma unroll
        for(int nt=0;nt<4;++nt)
          acc[g][nt]=__builtin_amdgcn_mfma_f32_16x16x32_bf16(A[g][c],B[nt],acc[g][nt],0,0,0);
    }
#pragma unroll
    for(int nt=0;nt<4;++nt){
      int nd=n0+16*nt+lo;
      if(nd<NN){
        unsigned short* p = Hp + (size_t)nd*G4 + w*64 + hi*16;
        uint4 q0, q1;
        q0.x=cvt_pk_bf16(acc[0][nt][0]+bb[0][0], acc[0][nt][1]+bb[0][1]);
        q0.y=cvt_pk_bf16(acc[0][nt][2]+bb[0][2], acc[0][nt][3]+bb[0][3]);
        q0.z=cvt_pk_bf16(acc[1][nt][0]+bb[1][0], acc[1][nt][1]+bb[1][1]);
        q0.w=cvt_pk_bf16(acc[1][nt][2]+bb[1][2], acc[1][nt][3]+bb[1][3]);
        q1.x=cvt_pk_bf16(acc[2][nt][0]+bb[2][0], acc[2][nt][1]+bb[2][1]);
        q1.y=cvt_pk_bf16(acc[2][nt][2]+bb[2][2], acc[2][nt][3]+bb[2][3]);
        q1.z=cvt_pk_bf16(acc[3][nt][0]+bb[3][0], acc[3][nt][1]+bb[3][1]);
        q1.w=cvt_pk_bf16(acc[3][nt][2]+bb[3][2], acc[3][nt][3]+bb[3][3]);
        *(uint4*)p = q0;
        *(uint4*)(p+8) = q1;
      }
    }
  }
}

// unpack one lane's 32B Hp chunk into the 4-gate accumulator init
static __device__ __forceinline__ void unpack_acc(const uint4 q[2], f32x4 acc[4]){
  acc[0][0]=lo16f(q[0].x); acc[0][1]=hi16f(q[0].x); acc[0][2]=lo16f(q[0].y); acc[0][3]=hi16f(q[0].y);
  acc[1][0]=lo16f(q[0].z); acc[1][1]=hi16f(q[0].z); acc[1][2]=lo16f(q[0].w); acc[1][3]=hi16f(q[0].w);
  acc[2][0]=lo16f(q[1].x); acc[2][1]=hi16f(q[1].x); acc[2][2]=lo16f(q[1].y); acc[2][3]=hi16f(q[1].y);
  acc[3][0]=lo16f(q[1].z); acc[3][1]=hi16f(q[1].z); acc[3][2]=lo16f(q[1].w); acc[3][3]=hi16f(q[1].w);
}

// LSTM cell, log2-domain prescaled gates, T-domain cell state C = c*2log2e (r10 proven).
static __device__ __forceinline__ void cell_update(const f32x4 acc[4], float C[4],
                                                   char* wb, int waddr){
  float hv[4];
#pragma unroll
  for(int r=0;r<4;++r){
    float ei=fexp2(acc[0][r]);
    float ef=fexp2(acc[1][r]);
    float eg=fexp2(acc[2][r]);
    float eo=fexp2(acc[3][r]);
    float itgT=__builtin_fmaf(eg, TLOG2E, -TLOG2E)*frcp((1.f+ei)*(1.f+eg));
    float Cn=__builtin_fmaf(C[r], frcp(1.f+ef), itgT);
    C[r]=Cn;
    float ec=fexp2(Cn);
    hv[r]=(ec-1.f)*frcp((1.f+eo)*(1.f+ec));
  }
  uint2 pk;
  pk.x=cvt_pk_bf16(hv[0],hv[1]);
  pk.y=cvt_pk_bf16(hv[2],hv[3]);
  *(uint2*)(wb + waddr) = pk;
}

// ---------------- Phase 2: LSTM scan, 48 nodes/block (3 groups), ONE barrier per t -----
// Grid = 417 (all co-resident -> single epoch; was 625 pairs = 2 epochs).
// Per t: 3 group-phases in one basic block -- the scheduler interleaves phase g+1's
// ds_reads/MFMA under phase g's cell-trans latency (compiler-level stagger, no
// cross-barrier acc registers). hp double-buffered by t parity (no read/write race).
// Gathers pipelined one phase ahead through statically-renamed qA/qB/qC; vmcnt spans
// the barrier (lgkm-only drain).
__global__ __launch_bounds__(512,1) void k_lstm(
    const float* __restrict__ h, const int* __restrict__ nbr,
    const float* __restrict__ W_hh, const unsigned short* __restrict__ Hp,
    const float* __restrict__ W_out, const float* __restrict__ b_out,
    float* __restrict__ out)
{
  __shared__ unsigned short hpd[3][2][16*HH];  // 24 KB: [group][t-parity][16 nodes x 128 dims]
  __shared__ int nlds[DEG*NPB];                // transposed: nlds[t][node] = nbr_idx*G4, 6 KB
  const int tid=threadIdx.x, w=tid>>6, lane=tid&63, lo=lane&15, hi=lane>>4;
  const int n0=blockIdx.x*NPB;
  const int swz=(lo&7)<<4;
  const int woff=w*64+hi*16;                   // lane's Hp chunk offset (shorts)
  const int waddr=((lo*256 + 32*w + 8*hi) ^ swz);
  const float SC[4]={NLOG2E,NLOG2E,TLOG2E,NLOG2E};

  s16x8 A[4][4];                               // W_hh fragments (prescaled), 64 VGPR
#pragma unroll
  for(int g=0;g<4;++g){
    const float* wr=W_hh+(size_t)(128*g+16*w+lo)*HH+8*hi;
#pragma unroll
    for(int c=0;c<4;++c) A[g][c]=ld8bf_s(wr+32*c, SC[g]);
  }
  {
#pragma unroll
    for(int g=0;g<3;++g){                      // zero read-parity buffers hpd[g][0]
      unsigned* z=(unsigned*)&hpd[g][0][0];
      z[tid]=0u; z[tid+512]=0u;                // 1024 u32 per buffer
    }
#pragma unroll
    for(int i=0;i<3;++i){                      // stage neighbor offsets transposed, clamped
      int idx=tid+512*i;                       // 0..1535 = node*32 + t
      int node=idx>>5;
      int src=n0+node; if(src>=NN) src=NN-1;
      nlds[(idx&31)*NPB + node] = nbr[src*DEG + (idx&31)]*G4;
    }
  }
  __syncthreads();

  float cst[3][4]={{0.f,0.f,0.f,0.f},{0.f,0.f,0.f,0.f},{0.f,0.f,0.f,0.f}};  // C-state

  // prologue gather: qA = (t=0, G0)
  uint4 qA[2], qB[2], qC[2];
  {
    const unsigned short* gp=Hp+(size_t)nlds[lo]+woff;
    qA[0]=*(const uint4*)gp; qA[1]=*(const uint4*)(gp+8);
  }

#define PHASE(g, QUSE, QLOAD, LOFF) { \
    { const unsigned short* gp_=Hp+(size_t)nlds[LOFF]+woff; \
      QLOAD[0]=*(const uint4*)gp_; QLOAD[1]=*(const uint4*)(gp_+8); } \
    s16x8 Bg[4]; \
    const char* rb_=(const char*)&hpd[g][t&1][0]; \
    _Pragma("unroll") \
    for(int c=0;c<4;++c) Bg[c]=*(const s16x8*)(rb_ + (((lo*256 + 64*c + 16*hi)) ^ swz)); \
    f32x4 acc_[4]; \
    unpack_acc(QUSE, acc_); \
    _Pragma("unroll") \
    for(int c=0;c<4;++c) \
      _Pragma("unroll") \
      for(int gg=0;gg<4;++gg) \
        acc_[gg]=__builtin_amdgcn_mfma_f32_16x16x32_bf16(A[gg][c],Bg[c],acc_[gg],0,0,0); \
    cell_update(acc_, cst[g], (char*)&hpd[g][(t+1)&1][0], waddr); }

  for(int t=0;t<DEG;++t){
    const int tn=(t+1<DEG)? t+1 : t;           // clamp: last dummy load re-reads t=31
    PHASE(0, qA, qB, t*NPB + 16 + lo)          // use (t,G0); load (t,G1)
    PHASE(1, qB, qC, t*NPB + 32 + lo)          // use (t,G1); load (t,G2)
    PHASE(2, qC, qA, tn*NPB + lo)              // use (t,G2); load (t+1,G0)
    asm volatile("s_waitcnt lgkmcnt(0)\n\ts_barrier" ::: "memory");
  }
#undef PHASE

  // ---- fused output projection: out = relu([h, agg] @ W_out^T + b_out) ----
  // agg for group g is in hpd[g][0] (t=31 wrote parity (31+1)&1 = 0).
  s16x8 AO[8];
  {
    const float* wr=W_out+(size_t)(16*w+lo)*256+8*hi;
#pragma unroll
    for(int c=0;c<8;++c) AO[c]=ld8bf(wr+32*c);
  }
  const int ob=16*w+4*hi;
  f32x4 bias=*(const f32x4*)(b_out+ob);
#pragma unroll
  for(int g=0;g<3;++g){
    const int node=n0+g*16+lo;
    const int nc = (node<NN)? node : NN-1;
    s16x8 BB[8];
    const float* hr=h+(size_t)nc*DD+8*hi;
#pragma unroll
    for(int c=0;c<4;++c) BB[c]=ld8bf(hr+32*c);
    const char* rb=(const char*)&hpd[g][0][0];
#pragma unroll
    for(int c=0;c<4;++c)
      BB[4+c]=*(const s16x8*)(rb + (((lo*256 + 64*c + 16*hi)) ^ swz));
    f32x4 acc=(f32x4)0.f;
#pragma unroll
    for(int c=0;c<8;++c) acc=__builtin_amdgcn_mfma_f32_16x16x32_bf16(AO[c],BB[c],acc,0,0,0);
#pragma unroll
    for(int r=0;r<4;++r){ float v=acc[r]+bias[r]; acc[r]=v>0.f?v:0.f; }
    if(node<NN) *(f32x4*)(out+(size_t)node*HH+ob)=acc;
  }
}

extern "C" void kernel_launch(void* const* d_in, const int* in_sizes, int n_in,
                              void* d_out, int out_size, void* d_ws, size_t ws_size,
                              hipStream_t stream)
{
  const float* h     = (const float*)d_in[0];
  const int*   nbr   = (const int*)d_in[1];
  const float* W_ih  = (const float*)d_in[2];
  const float* W_hh  = (const float*)d_in[3];
  const float* b_ih  = (const float*)d_in[4];
  const float* b_hh  = (const float*)d_in[5];
  const float* W_out = (const float*)d_in[6];
  const float* b_out = (const float*)d_in[7];
  unsigned short* Hp = (unsigned short*)d_ws;   // 20000*512*2B = 20.48 MB

  k_hp<<<256, 512, 0, stream>>>(h, W_ih, b_ih, b_hh, Hp);
  k_lstm<<<NBLK, 512, 0, stream>>>(h, nbr, W_hh, Hp, W_out, b_out, (float*)d_out);
}

// Round 12
// 208.940 us; speedup vs baseline: 1.0144x; 1.0144x over previous
//
#include <hip/hip_runtime.h>

#define NN 20000
#define DD 128
#define HH 128
#define G4 512
#define DEG 32
#define NPB 32     // nodes per pair: 2 MFMA groups of 16
#define PAIRS 625  // NN/NPB
#define GRID2 512  // exactly 2 blocks/CU resident; extra pairs work-stolen

typedef __attribute__((ext_vector_type(4))) float f32x4;
typedef __attribute__((ext_vector_type(8))) short s16x8;

#ifndef __has_builtin
#define __has_builtin(x) 0
#endif

__device__ int g_cnt;   // next pair index for work stealing; re-armed by k_hp each launch

// Builtin transcendentals ONLY (round-9 lesson: raw inline-asm v_exp/v_rcp bypasses
// the compiler's trans-use hazard handling -> numerical corruption).
static __device__ __forceinline__ float fexp2(float x){
#if __has_builtin(__builtin_amdgcn_exp2f)
  return __builtin_amdgcn_exp2f(x);
#else
  return exp2f(x);
#endif
}
static __device__ __forceinline__ float frcp(float x){
#if __has_builtin(__builtin_amdgcn_rcpf)
  return __builtin_amdgcn_rcpf(x);
#else
  return 1.f/x;
#endif
}

// packed f32x2 -> bf16x2 (RNE) — VOP3, no trans hazard; proven since round 1
static __device__ __forceinline__ unsigned cvt_pk_bf16(float lo, float hi){
  unsigned r;
  asm("v_cvt_pk_bf16_f32 %0, %1, %2" : "=v"(r) : "v"(lo), "v"(hi));
  return r;
}
static __device__ __forceinline__ s16x8 ld8bf(const float* __restrict__ p){
  f32x4 a = *(const f32x4*)p;
  f32x4 b = *(const f32x4*)(p+4);
  union{unsigned u[4]; s16x8 v;} z;
  z.u[0]=cvt_pk_bf16(a[0],a[1]);
  z.u[1]=cvt_pk_bf16(a[2],a[3]);
  z.u[2]=cvt_pk_bf16(b[0],b[1]);
  z.u[3]=cvt_pk_bf16(b[2],b[3]);
  return z.v;
}
// scaled variant: multiply by s before bf16 conversion (log2e pre-scaling)
static __device__ __forceinline__ s16x8 ld8bf_s(const float* __restrict__ p, float s){
  f32x4 a = *(const f32x4*)p;
  f32x4 b = *(const f32x4*)(p+4);
  union{unsigned u[4]; s16x8 v;} z;
  z.u[0]=cvt_pk_bf16(a[0]*s,a[1]*s);
  z.u[1]=cvt_pk_bf16(a[2]*s,a[3]*s);
  z.u[2]=cvt_pk_bf16(b[0]*s,b[1]*s);
  z.u[3]=cvt_pk_bf16(b[2]*s,b[3]*s);
  return z.v;
}
// bf16 packed in u32 -> f32 (bf16 in high 16 bits IS the f32 bit pattern)
static __device__ __forceinline__ float lo16f(unsigned u){
  union{unsigned x; float f;} v; v.x = u << 16; return v.f;
}
static __device__ __forceinline__ float hi16f(unsigned u){
  union{unsigned x; float f;} v; v.x = u & 0xffff0000u; return v.f;
}
#define NLOG2E -1.44269504f
#define TLOG2E  2.88539008f

// ---------------- Phase 1: Hp = (h @ W_ih^T + b_ih + b_hh) * S[gate], bf16 ----------------
// PERMUTED layout: element (n, gatecol=128g+16w+4hi+r) stored at n*512 + w*64 + hi*16 + g*4 + r.
// PRE-SCALED by S = {-log2e, -log2e, 2log2e, -log2e} per gate (acc feeds exp2 directly).
__global__ __launch_bounds__(512,2) void k_hp(
    const float* __restrict__ h, const float* __restrict__ W_ih,
    const float* __restrict__ b_ih, const float* __restrict__ b_hh,
    unsigned short* __restrict__ Hp)
{
  if(blockIdx.x==0 && threadIdx.x==0) g_cnt = GRID2;  // arm the k_lstm work-steal counter
  const int tid=threadIdx.x, w=tid>>6, lane=tid&63, lo=lane&15, hi=lane>>4;
  const float SC[4]={NLOG2E,NLOG2E,TLOG2E,NLOG2E};
  s16x8 A[4][4];
#pragma unroll
  for(int g=0;g<4;++g){
    const float* wr=W_ih+(size_t)(128*g+16*w+lo)*DD+8*hi;
#pragma unroll
    for(int c=0;c<4;++c) A[g][c]=ld8bf_s(wr+32*c, SC[g]);
  }
  f32x4 bb[4];
#pragma unroll
  for(int g=0;g<4;++g){
    const int gcb=128*g+16*w+4*hi;
    bb[g]=(*(const f32x4*)(b_ih+gcb) + *(const f32x4*)(b_hh+gcb))*SC[g];
  }
  // grid 256, blocks 0..56 take a second 64-node chunk (313 chunks total)
  const int nchunk = (blockIdx.x < 57) ? 2 : 1;
  for(int cc=0; cc<nchunk; ++cc){
    const int n0 = ((cc? 256+blockIdx.x : blockIdx.x))*64;
    f32x4 acc[4][4];
#pragma unroll
    for(int g=0;g<4;++g)
#pragma unroll
      for(int nt=0;nt<4;++nt) acc[g][nt]=(f32x4)0.f;
#pragma unroll
    for(int c=0;c<4;++c){
      s16x8 B[4];
#pragma unroll
      for(int nt=0;nt<4;++nt){
        int nd=n0+16*nt+lo; if(nd>=NN) nd=NN-1;
        B[nt]=ld8bf(h+(size_t)nd*DD+32*c+8*hi);
      }
#pragma unroll
      for(int g=0;g<4;++g)
#pragma unroll
        for(int nt=0;nt<4;++nt)
          acc[g][nt]=__builtin_amdgcn_mfma_f32_16x16x32_bf16(A[g][c],B[nt],acc[g][nt],0,0,0);
    }
#pragma unroll
    for(int nt=0;nt<4;++nt){
      int nd=n0+16*nt+lo;
      if(nd<NN){
        unsigned short* p = Hp + (size_t)nd*G4 + w*64 + hi*16;
        uint4 q0, q1;
        q0.x=cvt_pk_bf16(acc[0][nt][0]+bb[0][0], acc[0][nt][1]+bb[0][1]);
        q0.y=cvt_pk_bf16(acc[0][nt][2]+bb[0][2], acc[0][nt][3]+bb[0][3]);
        q0.z=cvt_pk_bf16(acc[1][nt][0]+bb[1][0], acc[1][nt][1]+bb[1][1]);
        q0.w=cvt_pk_bf16(acc[1][nt][2]+bb[1][2], acc[1][nt][3]+bb[1][3]);
        q1.x=cvt_pk_bf16(acc[2][nt][0]+bb[2][0], acc[2][nt][1]+bb[2][1]);
        q1.y=cvt_pk_bf16(acc[2][nt][2]+bb[2][2], acc[2][nt][3]+bb[2][3]);
        q1.z=cvt_pk_bf16(acc[3][nt][0]+bb[3][0], acc[3][nt][1]+bb[3][1]);
        q1.w=cvt_pk_bf16(acc[3][nt][2]+bb[3][2], acc[3][nt][3]+bb[3][3]);
        *(uint4*)p = q0;
        *(uint4*)(p+8) = q1;
      }
    }
  }
}

// unpack one lane's 32B Hp chunk into the 4-gate accumulator init
static __device__ __forceinline__ void unpack_acc(const uint4 q[2], f32x4 acc[4]){
  acc[0][0]=lo16f(q[0].x); acc[0][1]=hi16f(q[0].x); acc[0][2]=lo16f(q[0].y); acc[0][3]=hi16f(q[0].y);
  acc[1][0]=lo16f(q[0].z); acc[1][1]=hi16f(q[0].z); acc[1][2]=lo16f(q[0].w); acc[1][3]=hi16f(q[0].w);
  acc[2][0]=lo16f(q[1].x); acc[2][1]=hi16f(q[1].x); acc[2][2]=lo16f(q[1].y); acc[2][3]=hi16f(q[1].y);
  acc[3][0]=lo16f(q[1].z); acc[3][1]=hi16f(q[1].z); acc[3][2]=lo16f(q[1].w); acc[3][3]=hi16f(q[1].w);
}

// LSTM cell, log2-domain prescaled gates, T-domain cell state C = c*2log2e (r10 proven).
static __device__ __forceinline__ void cell_update(const f32x4 acc[4], float C[4],
                                                   char* wb, int waddr){
  float hv[4];
#pragma unroll
  for(int r=0;r<4;++r){
    float ei=fexp2(acc[0][r]);
    float ef=fexp2(acc[1][r]);
    float eg=fexp2(acc[2][r]);
    float eo=fexp2(acc[3][r]);
    float itgT=__builtin_fmaf(eg, TLOG2E, -TLOG2E)*frcp((1.f+ei)*(1.f+eg));
    float Cn=__builtin_fmaf(C[r], frcp(1.f+ef), itgT);
    C[r]=Cn;
    float ec=fexp2(Cn);
    hv[r]=(ec-1.f)*frcp((1.f+eo)*(1.f+ec));
  }
  uint2 pk;
  pk.x=cvt_pk_bf16(hv[0],hv[1]);
  pk.y=cvt_pk_bf16(hv[2],hv[3]);
  *(uint2*)(wb + waddr) = pk;
}

// ---------------- Phase 2: LSTM scan — r11 one-barrier-per-t interior + r5 work-steal -----
// Grid = 512 (2 blocks/CU everywhere). Each block: 32 nodes = 2 groups of 16; per t the
// two group-phases run back-to-back in ONE barrier interval (parity-double-buffered hpd,
// compiler interleaves phase 1's ds_read/MFMA under phase 0's trans chain = r11's 1.5x
// phase rate). Gathers pipelined one phase ahead via renamed qA/qB (vmcnt spans barrier).
// Blocks steal pairs 512..624 from a device atomic -> balanced CU load (r5).
__global__ __launch_bounds__(512,2) void k_lstm(
    const float* __restrict__ h, const int* __restrict__ nbr,
    const float* __restrict__ W_hh, const unsigned short* __restrict__ Hp,
    const float* __restrict__ W_out, const float* __restrict__ b_out,
    float* __restrict__ out)
{
  __shared__ unsigned short hpd[2][2][16*HH];  // 16 KB: [group][t-parity][16 nodes x 128 dims]
  __shared__ int nlds[DEG*NPB];                // transposed: nlds[t][node] = nbr_idx*G4, 4 KB
  __shared__ int spair;
  const int tid=threadIdx.x, w=tid>>6, lane=tid&63, lo=lane&15, hi=lane>>4;
  const int swz=(lo&7)<<4;
  const int woff=w*64+hi*16;                   // lane's Hp chunk offset (shorts)
  const int waddr=((lo*256 + 32*w + 8*hi) ^ swz);
  const float SC[4]={NLOG2E,NLOG2E,TLOG2E,NLOG2E};

  s16x8 A[4][4];                               // W_hh fragments (prescaled), 64 VGPR
#pragma unroll
  for(int g=0;g<4;++g){
    const float* wr=W_hh+(size_t)(128*g+16*w+lo)*HH+8*hi;
#pragma unroll
    for(int c=0;c<4;++c) A[g][c]=ld8bf_s(wr+32*c, SC[g]);
  }

  int pair = blockIdx.x;
  for(;;){
    const int n0 = pair*NPB;
    {
#pragma unroll
      for(int g=0;g<2;++g){                    // zero read-parity buffers hpd[g][0]
        unsigned* z=(unsigned*)&hpd[g][0][0];
        z[tid]=0u; z[tid+512]=0u;              // 1024 u32 per buffer
      }
#pragma unroll
      for(int i=0;i<2;++i){                    // stage neighbor offsets transposed, pre-scaled
        int idx=tid+512*i;
        nlds[(idx&31)*NPB + (idx>>5)] = nbr[n0*DEG + idx]*G4;
      }
    }
    __syncthreads();

    float cst[2][4]={{0.f,0.f,0.f,0.f},{0.f,0.f,0.f,0.f}};  // C-state (x 2log2e)

    // prologue gather: qA = (t=0, G0)
    uint4 qA[2], qB[2];
    {
      const unsigned short* gp=Hp+(size_t)nlds[lo]+woff;
      qA[0]=*(const uint4*)gp; qA[1]=*(const uint4*)(gp+8);
    }

#define PHASE(g, QUSE, QLOAD, LOFF) { \
    { const unsigned short* gp_=Hp+(size_t)nlds[LOFF]+woff; \
      QLOAD[0]=*(const uint4*)gp_; QLOAD[1]=*(const uint4*)(gp_+8); } \
    s16x8 Bg[4]; \
    const char* rb_=(const char*)&hpd[g][t&1][0]; \
    _Pragma("unroll") \
    for(int c=0;c<4;++c) Bg[c]=*(const s16x8*)(rb_ + (((lo*256 + 64*c + 16*hi)) ^ swz)); \
    f32x4 acc_[4]; \
    unpack_acc(QUSE, acc_); \
    _Pragma("unroll") \
    for(int c=0;c<4;++c) \
      _Pragma("unroll") \
      for(int gg=0;gg<4;++gg) \
        acc_[gg]=__builtin_amdgcn_mfma_f32_16x16x32_bf16(A[gg][c],Bg[c],acc_[gg],0,0,0); \
    cell_update(acc_, cst[g], (char*)&hpd[g][(t+1)&1][0], waddr); }

    for(int t=0;t<DEG;++t){
      const int tn=(t+1<DEG)? t+1 : t;         // clamp: last dummy load re-reads t=31
      PHASE(0, qA, qB, t*NPB + 16 + lo)        // use (t,G0); load (t,G1)
      PHASE(1, qB, qA, tn*NPB + lo)            // use (t,G1); load (t+1,G0)
      asm volatile("s_waitcnt lgkmcnt(0)\n\ts_barrier" ::: "memory");
    }
#undef PHASE

    // ---- fused output projection: out = relu([h, agg] @ W_out^T + b_out) ----
    // agg for group g is in hpd[g][0] (t=31 wrote parity (31+1)&1 = 0).
    s16x8 AO[8];
    {
      const float* wr=W_out+(size_t)(16*w+lo)*256+8*hi;
#pragma unroll
      for(int c=0;c<8;++c) AO[c]=ld8bf(wr+32*c);
    }
    const int ob=16*w+4*hi;
    f32x4 bias=*(const f32x4*)(b_out+ob);
#pragma unroll
    for(int g=0;g<2;++g){
      const int node=n0+g*16+lo;
      s16x8 BB[8];
      const float* hr=h+(size_t)node*DD+8*hi;
#pragma unroll
      for(int c=0;c<4;++c) BB[c]=ld8bf(hr+32*c);
      const char* rb=(const char*)&hpd[g][0][0];
#pragma unroll
      for(int c=0;c<4;++c)
        BB[4+c]=*(const s16x8*)(rb + (((lo*256 + 64*c + 16*hi)) ^ swz));
      f32x4 acc=(f32x4)0.f;
#pragma unroll
      for(int c=0;c<8;++c) acc=__builtin_amdgcn_mfma_f32_16x16x32_bf16(AO[c],BB[c],acc,0,0,0);
#pragma unroll
      for(int r=0;r<4;++r){ float v=acc[r]+bias[r]; acc[r]=v>0.f?v:0.f; }
      *(f32x4*)(out+(size_t)node*HH+ob)=acc;
    }

    // ---- steal the next pair; barrier also protects LDS reuse across pairs ----
    if(tid==0) spair = atomicAdd(&g_cnt, 1);
    __syncthreads();
    pair = spair;
    if(pair >= PAIRS) break;
  }
}

extern "C" void kernel_launch(void* const* d_in, const int* in_sizes, int n_in,
                              void* d_out, int out_size, void* d_ws, size_t ws_size,
                              hipStream_t stream)
{
  const float* h     = (const float*)d_in[0];
  const int*   nbr   = (const int*)d_in[1];
  const float* W_ih  = (const float*)d_in[2];
  const float* W_hh  = (const float*)d_in[3];
  const float* b_ih  = (const float*)d_in[4];
  const float* b_hh  = (const float*)d_in[5];
  const float* W_out = (const float*)d_in[6];
  const float* b_out = (const float*)d_in[7];
  unsigned short* Hp = (unsigned short*)d_ws;   // 20000*512*2B = 20.48 MB

  k_hp<<<256, 512, 0, stream>>>(h, W_ih, b_ih, b_hh, Hp);
  k_lstm<<<GRID2, 512, 0, stream>>>(h, nbr, W_hh, Hp, W_out, b_out, (float*)d_out);
}